// Round 4
// baseline (795.779 us; speedup 1.0000x reference)
//
#include <hip/hip_runtime.h>
#include <math.h>

#define N 8192
#define M 8192
#define C 96
#define OUT 20
#define LG 2048

#define NSPA 32   // n-splits for argmin pass (pass A): grid 32x32 = 4 blocks/CU
#define NSPB 32   // m-stride for uw pass (pass B):     grid 32x32 = 4 blocks/CU

// ---------------- workspace layout (bytes) ----------------
constexpr size_t OFF_DIFF  = 0;
constexpr size_t OFF_AL    = 256;
constexpr size_t OFF_ANORM = OFF_AL    + (size_t)M*3*4;
constexpr size_t OFF_BNORM = OFF_ANORM + (size_t)M*C*4;
constexpr size_t OFF_NMF2  = OFF_BNORM + (size_t)N*C*4;
constexpr size_t OFF_UPDF  = OFF_NMF2  + (size_t)N*4;
constexpr size_t OFF_GTC   = OFF_UPDF  + (size_t)M*4;
constexpr size_t OFF_SMI   = OFF_GTC   + (size_t)M*4;
constexpr size_t OFF_PERM  = OFF_SMI   + (size_t)M*4;
constexpr size_t OFF_MIDF  = OFF_PERM  + (size_t)M*4;
constexpr size_t OFF_MIDN2 = OFF_MIDF  + (size_t)(M+128)*C*4;
constexpr size_t OFF_MIDC  = OFF_MIDN2 + (size_t)(M+128)*4;
constexpr size_t OFF_CLS   = OFF_MIDC  + (size_t)(M+128)*3*4;
constexpr size_t OFF_PAV   = OFF_CLS   + (size_t)(M+128)*4;
constexpr size_t OFF_PAI   = OFF_PAV   + (size_t)M*NSPA*4;
constexpr size_t OFF_UWACC = OFF_PAI   + (size_t)M*NSPA*4;   // N*OUT floats
constexpr size_t OFF_VALS  = OFF_UWACC + (size_t)N*OUT*4;
constexpr size_t OFF_POS   = OFF_VALS  + (size_t)LG*4;
constexpr size_t OFF_MAXV  = OFF_POS   + (size_t)N*4;
constexpr size_t OFF_AMAX  = OFF_MAXV  + (size_t)N*4;
constexpr size_t OFF_FLAGS = OFF_AMAX  + (size_t)N*4;
constexpr size_t OFF_CNT   = OFF_FLAGS + 64;                 // 20 ints
constexpr size_t OFF_META  = OFF_CNT   + 128;                // [0]=Mact [1]=ntiles [2..21]=cursor

// ---------------------------------------------------------------- 4x4 inverse
__global__ void k_diff(const float* __restrict__ posses, float* __restrict__ diff) {
    if (threadIdx.x != 0 || blockIdx.x != 0) return;
    float a[4][8];
    for (int i = 0; i < 4; i++)
        for (int j = 0; j < 4; j++) {
            a[i][j]     = posses[16 + i*4 + j];   // posses[1]
            a[i][4 + j] = (i == j) ? 1.f : 0.f;
        }
    for (int col = 0; col < 4; col++) {
        int piv = col; float mx = fabsf(a[col][col]);
        for (int r = col + 1; r < 4; r++) {
            float v = fabsf(a[r][col]);
            if (v > mx) { mx = v; piv = r; }
        }
        if (piv != col)
            for (int j = 0; j < 8; j++) { float t = a[col][j]; a[col][j] = a[piv][j]; a[piv][j] = t; }
        float inv = 1.0f / a[col][col];
        for (int j = 0; j < 8; j++) a[col][j] *= inv;
        for (int r = 0; r < 4; r++) {
            if (r == col) continue;
            float f = a[r][col];
            for (int j = 0; j < 8; j++) a[r][j] -= f * a[col][j];
        }
    }
    for (int i = 0; i < 4; i++)
        for (int j = 0; j < 4; j++) {
            float s = 0.f;
            for (int k = 0; k < 4; k++) s += a[i][4 + k] * posses[k*4 + j];
            diff[i*4 + j] = s;
        }
}

// ---------------------------------------------------------------- per-m prep
__global__ void k_prep_m(const float* __restrict__ ssf, const float* __restrict__ scoords,
                         const float* __restrict__ gt, const int* __restrict__ ran_mask,
                         const float* __restrict__ diff,
                         float* __restrict__ al, float* __restrict__ anorm,
                         float* __restrict__ updf, int* __restrict__ gtcls) {
    int m = blockIdx.x * 256 + threadIdx.x;
    if (m >= M) return;
    float x = scoords[m*3], y = scoords[m*3+1], z = scoords[m*3+2];
    #pragma unroll
    for (int j = 0; j < 3; j++)
        al[m*3 + j] = diff[j*4+0]*x + diff[j*4+1]*y + diff[j*4+2]*z + diff[j*4+3];
    float s = 0.f;
    const float4* r4 = (const float4*)(ssf + (size_t)m * C);
    float4 row[24];
    #pragma unroll
    for (int c = 0; c < 24; c++) {
        float4 v = r4[c];
        row[c] = v;
        s += v.x*v.x + v.y*v.y + v.z*v.z + v.w*v.w;
    }
    float rn = 1.0f / sqrtf(s);
    float4* w4 = (float4*)(anorm + (size_t)m * C);
    #pragma unroll
    for (int c = 0; c < 24; c++) {
        float4 v = row[c];
        v.x *= rn; v.y *= rn; v.z *= rn; v.w *= rn;
        w4[c] = v;
    }
    int best = 0; float bv = gt[(size_t)m*OUT];
    #pragma unroll
    for (int k = 1; k < OUT; k++) {
        float v = gt[(size_t)m*OUT + k];
        if (v > bv) { bv = v; best = k; }
    }
    gtcls[m] = best;
    updf[m] = (best < 9 || m < LG || ran_mask[m] == 1) ? 1.f : 0.f;
}

// ---------------------------------------------------------------- per-n prep
__global__ void k_prep_n(const float* __restrict__ mf, float* __restrict__ bnorm,
                         float* __restrict__ nmf2) {
    int n = blockIdx.x * 256 + threadIdx.x;
    if (n >= N) return;
    float s = 0.f;
    const float4* r4 = (const float4*)(mf + (size_t)n * C);
    float4 row[24];
    #pragma unroll
    for (int c = 0; c < 24; c++) {
        float4 v = r4[c];
        row[c] = v;
        s += v.x*v.x + v.y*v.y + v.z*v.z + v.w*v.w;
    }
    nmf2[n] = s;
    float rn = 1.0f / sqrtf(s);
    float4* w4 = (float4*)(bnorm + (size_t)n * C);
    #pragma unroll
    for (int c = 0; c < 24; c++) {
        float4 v = row[c];
        v.x *= rn; v.y *= rn; v.z *= rn; v.w *= rn;
        w4[c] = v;
    }
}

// ---------------------------------------------------------------- pass A: argmin over n per m
// Lane-private: each lane holds its anorm row in 96 VGPRs; the n-row is
// wave-uniform (scalar/broadcast loads). No LDS, no barriers, no shuffles.
__global__ __launch_bounds__(256, 3) void k_argmin(
        const float* __restrict__ anorm, const float* __restrict__ bnorm,
        const float* __restrict__ al, const float* __restrict__ ori,
        float* __restrict__ pav, int* __restrict__ pai) {
    const int t = threadIdx.x;
    const int m = blockIdx.x * 256 + t;
    const int sp = blockIdx.y;

    float a[C];
    {
        const float4* ar = (const float4*)(anorm + (size_t)m * C);
        #pragma unroll
        for (int c = 0; c < 24; c++) {
            float4 v = ar[c];
            a[c*4+0] = v.x; a[c*4+1] = v.y; a[c*4+2] = v.z; a[c*4+3] = v.w;
        }
    }
    const float mcx = al[m*3+0], mcy = al[m*3+1], mcz = al[m*3+2];

    float best = 3.4e38f; int bidx = 0;
    const int nbeg = sp * (N / NSPA);
    const int nend = nbeg + (N / NSPA);
    for (int n = nbeg; n < nend; ++n) {
        const float4* br = (const float4*)(bnorm + (size_t)n * C);
        float d0 = 0.f, d1 = 0.f, d2 = 0.f, d3 = 0.f;
        #pragma unroll
        for (int c = 0; c < 24; ++c) {
            float4 bv = br[c];
            d0 = fmaf(a[c*4+0], bv.x, d0);
            d1 = fmaf(a[c*4+1], bv.y, d1);
            d2 = fmaf(a[c*4+2], bv.z, d2);
            d3 = fmaf(a[c*4+3], bv.w, d3);
        }
        float dot = (d0 + d1) + (d2 + d3);
        float bx = ori[n*3+0], by = ori[n*3+1], bz = ori[n*3+2];
        float dx = mcx - bx, dy = mcy - by, dz = mcz - bz;
        float dd = dx*dx + dy*dy + dz*dz;
        float sim = 2.0f - dot - __expf(-2.0f*dd);
        if (sim < best) { best = sim; bidx = n; }   // strict <: earliest n wins
    }
    pav[(size_t)sp*M + m] = best;
    pai[(size_t)sp*M + m] = bidx;
}

__global__ void k_argmin_reduce(const float* __restrict__ pav, const int* __restrict__ pai,
                                int* __restrict__ smi, float* __restrict__ out_smi) {
    int m = blockIdx.x * 256 + threadIdx.x;
    if (m >= M) return;
    float best = 3.4e38f; int bidx = 0;
    for (int sp = 0; sp < NSPA; sp++) {
        float v = pav[(size_t)sp * M + m];
        int   i = pai[(size_t)sp * M + m];
        if (v < best || (v == best && i < bidx)) { best = v; bidx = i; }
    }
    smi[m] = bidx;
    out_smi[m] = (float)bidx;
}

// ---------------------------------------------------------------- counting sort by class (active only)
__global__ void k_hist(const int* __restrict__ gtcls, const float* __restrict__ updf,
                       int* __restrict__ cnt) {
    __shared__ int h[OUT];
    int t = threadIdx.x;
    if (t < OUT) h[t] = 0;
    __syncthreads();
    int m = blockIdx.x * 256 + t;
    if (m < M && updf[m] != 0.f) atomicAdd(&h[gtcls[m]], 1);
    __syncthreads();
    if (t < OUT) atomicAdd(&cnt[t], h[t]);
}

__global__ void k_scan(const int* __restrict__ cnt, int* __restrict__ meta) {
    if (threadIdx.x != 0 || blockIdx.x != 0) return;
    int run = 0;
    for (int k = 0; k < OUT; k++) { meta[2 + k] = run; run += cnt[k]; }
    meta[0] = run;                    // Mact
    meta[1] = (run + 127) / 128;      // ntiles (unused now)
}

__global__ void k_permute(const int* __restrict__ gtcls, const float* __restrict__ updf,
                          int* __restrict__ meta, int* __restrict__ perm) {
    int m = blockIdx.x * 256 + threadIdx.x;
    if (m >= M) return;
    if (updf[m] == 0.f) return;
    int pos = atomicAdd(&meta[2 + gtcls[m]], 1);
    perm[pos] = m;
}

// gather sorted+compacted mid rows
__global__ void k_gather_sorted(const int* __restrict__ meta, const int* __restrict__ perm,
                                const int* __restrict__ smi, const int* __restrict__ gtcls,
                                const float* __restrict__ mf, const float* __restrict__ nmf2,
                                const float* __restrict__ ori,
                                float* __restrict__ midf, float* __restrict__ midn2,
                                float* __restrict__ midc, int* __restrict__ cls_s) {
    int r = blockIdx.x * 256 + threadIdx.x;
    int mact = meta[0];
    if (r >= mact) return;
    int m = perm[r];
    int s = smi[m];
    const float4* src = (const float4*)(mf + (size_t)s * C);
    float4* dst = (float4*)(midf + (size_t)r * C);
    #pragma unroll
    for (int q = 0; q < 24; q++) dst[q] = src[q];
    midn2[r] = nmf2[s];
    midc[r*3+0] = ori[s*3+0];
    midc[r*3+1] = ori[s*3+1];
    midc[r*3+2] = ori[s*3+2];
    cls_s[r] = gtcls[m];
}

// ---------------------------------------------------------------- pass B: class-binned weight sums
// Lane-private n-row in VGPRs; m-rows (sorted by class, compacted) are
// wave-uniform loads. Class runs are monotone -> one running sum, flushed
// to global uwacc[n][cls] by atomicAdd only at run boundaries.
__global__ __launch_bounds__(256, 3) void k_uw(
        const float* __restrict__ mf, const float* __restrict__ nmf2,
        const float* __restrict__ ori,
        const float* __restrict__ midf, const float* __restrict__ midn2,
        const float* __restrict__ midc, const int* __restrict__ cls_s,
        const int* __restrict__ meta, float* __restrict__ uwacc) {
    const int t = threadIdx.x;
    const int n = blockIdx.x * 256 + t;
    const int sp = blockIdx.y;
    const int mact = meta[0];

    float a[C];
    {
        const float4* ar = (const float4*)(mf + (size_t)n * C);
        #pragma unroll
        for (int c = 0; c < 24; c++) {
            float4 v = ar[c];
            a[c*4+0] = v.x; a[c*4+1] = v.y; a[c*4+2] = v.z; a[c*4+3] = v.w;
        }
    }
    const float n2  = nmf2[n];
    const float ncx = ori[n*3+0], ncy = ori[n*3+1], ncz = ori[n*3+2];

    float cur = 0.f; int curcls = -1;
    for (int mi = sp; mi < mact; mi += NSPB) {
        const float4* br = (const float4*)(midf + (size_t)mi * C);
        float d0 = 0.f, d1 = 0.f, d2 = 0.f, d3 = 0.f;
        #pragma unroll
        for (int c = 0; c < 24; ++c) {
            float4 bv = br[c];
            d0 = fmaf(a[c*4+0], bv.x, d0);
            d1 = fmaf(a[c*4+1], bv.y, d1);
            d2 = fmaf(a[c*4+2], bv.z, d2);
            d3 = fmaf(a[c*4+3], bv.w, d3);
        }
        float dot = (d0 + d1) + (d2 + d3);
        int cls = cls_s[mi];
        if (cls != curcls) {           // uniform, rare (<=20 takes per block)
            if (curcls >= 0) atomicAdd(&uwacc[(size_t)n*OUT + curcls], cur);
            curcls = cls; cur = 0.f;
        }
        float m2  = midn2[mi];
        float mcx = midc[mi*3+0], mcy = midc[mi*3+1], mcz = midc[mi*3+2];
        float fd = fmaxf(n2 + m2 - 2.0f*dot, 0.0f);
        float dx = ncx - mcx, dy = ncy - mcy, dz = ncz - mcz;
        float dc = dx*dx + dy*dy + dz*dz;
        cur += __expf(-8.0f*dc - (0.5f/0.09f)*fd);
    }
    if (curcls >= 0) atomicAdd(&uwacc[(size_t)n*OUT + curcls], cur);
}

__global__ void k_uw_final(const float* __restrict__ uwacc, const float* __restrict__ svp,
                           float* __restrict__ out_uw, float* __restrict__ out_spu) {
    int n = blockIdx.x * 256 + threadIdx.x;
    if (n >= N) return;
    float s[OUT]; float tot = 0.f;
    #pragma unroll
    for (int k = 0; k < OUT; k++) { s[k] = uwacc[(size_t)n*OUT + k]; tot += s[k]; }
    float rden = 1.0f / (tot + 1e-16f);
    float p[OUT]; float mx = -3.4e38f;
    #pragma unroll
    for (int k = 0; k < OUT; k++) { p[k] = svp[(size_t)n*OUT + k]; mx = fmaxf(mx, p[k]); }
    float es = 0.f;
    #pragma unroll
    for (int k = 0; k < OUT; k++) { p[k] = __expf(p[k] - mx); es += p[k]; }
    float res = 1.0f / es;
    #pragma unroll
    for (int k = 0; k < OUT; k++) {
        float uw = s[k] * rden;
        out_uw[(size_t)n*OUT + k] = uw;
        out_spu[(size_t)n*OUT + k] = 0.5f * (p[k] * res) + 0.5f * uw;
    }
}

// ---------------------------------------------------------------- scatter (lg rows, last-wins)
__global__ void k_scatter_pre(const int* __restrict__ smi, const int* __restrict__ gtcls,
                              const float* __restrict__ spu, float* __restrict__ vals,
                              int* __restrict__ pos, int* __restrict__ flags) {
    int i = blockIdx.x * 256 + threadIdx.x;
    if (i >= LG) return;
    int idx = smi[i];
    float v = spu[(size_t)idx*OUT + gtcls[i]];
    vals[i] = v;
    if (v > 0.1f) atomicOr(&flags[0], 1);
    atomicMax(&pos[idx], i);
}

__global__ void k_scatter_apply(const int* __restrict__ smi, const int* __restrict__ gtcls,
                                const float* __restrict__ vals, const int* __restrict__ pos,
                                const int* __restrict__ flags, float* __restrict__ spu) {
    int i = blockIdx.x * 256 + threadIdx.x;
    if (i >= LG) return;
    int idx = smi[i];
    if (pos[idx] != i) return;               // last occurrence wins (np semantics)
    float v = vals[i];
    bool tmp = flags[0] ? (v > 0.1f) : (v > 0.0f);
    if (!tmp) return;
    int cls = gtcls[i];
    #pragma unroll
    for (int k = 0; k < OUT; k++) spu[(size_t)idx*OUT + k] = (k == cls) ? 1.0f : 0.0f;
}

// ---------------------------------------------------------------- trust / finalize
__global__ void k_trust_pre(const float* __restrict__ spu, float* __restrict__ maxv,
                            int* __restrict__ amax, int* __restrict__ flags) {
    int n = blockIdx.x * 256 + threadIdx.x;
    if (n >= N) return;
    float best = spu[(size_t)n*OUT]; int bi = 0;
    #pragma unroll
    for (int k = 1; k < OUT; k++) {
        float v = spu[(size_t)n*OUT + k];
        if (v > best) { best = v; bi = k; }
    }
    maxv[n] = best; amax[n] = bi;
    if (best >= 0.9f) atomicOr(&flags[1], 1);
}

__global__ void k_finalize(const float* __restrict__ mf, const float* __restrict__ ori,
                           const float* __restrict__ maxv, const int* __restrict__ amax,
                           const int* __restrict__ flags,
                           float* __restrict__ out_trust, float* __restrict__ out_mf,
                           float* __restrict__ out_ori, float* __restrict__ out_pre) {
    int n = blockIdx.x * 256 + threadIdx.x;
    if (n >= N) return;
    float mv = maxv[n];
    bool tr = flags[1] ? (mv >= 0.9f) : (mv >= 0.85f);
    float m = tr ? 1.f : 0.f;
    out_trust[n] = m;
    const float4* src = (const float4*)(mf + (size_t)n * C);
    float4* dst = (float4*)(out_mf + (size_t)n * C);
    #pragma unroll
    for (int c = 0; c < 24; c++) {
        float4 v = src[c];
        v.x *= m; v.y *= m; v.z *= m; v.w *= m;
        dst[c] = v;
    }
    out_ori[n*3]   = ori[n*3]   * m;
    out_ori[n*3+1] = ori[n*3+1] * m;
    out_ori[n*3+2] = ori[n*3+2] * m;
    int bi = amax[n];
    #pragma unroll
    for (int k = 0; k < OUT; k++) out_pre[(size_t)n*OUT + k] = (k == bi) ? m : 0.f;
}

// ---------------------------------------------------------------- launch
extern "C" void kernel_launch(void* const* d_in, const int* in_sizes, int n_in,
                              void* d_out, int out_size, void* d_ws, size_t ws_size,
                              hipStream_t stream) {
    (void)in_sizes; (void)n_in; (void)out_size; (void)ws_size;
    const float* ssf     = (const float*)d_in[0];
    const float* scoords = (const float*)d_in[1];
    const float* gt      = (const float*)d_in[2];
    const float* svp     = (const float*)d_in[3];
    const float* mf      = (const float*)d_in[4];
    const float* ori     = (const float*)d_in[5];
    const float* posses  = (const float*)d_in[6];
    const int*   ran     = (const int*)d_in[7];

    float* out = (float*)d_out;
    float* out_trust = out;
    float* out_mf    = out_trust + N;
    float* out_ori   = out_mf + (size_t)N*C;
    float* out_pre   = out_ori + (size_t)N*3;
    float* out_uw    = out_pre + (size_t)N*OUT;
    float* out_spu   = out_uw  + (size_t)N*OUT;
    float* out_smi   = out_spu + (size_t)N*OUT;

    char* ws = (char*)d_ws;
    float* w_diff  = (float*)(ws + OFF_DIFF);
    float* w_al    = (float*)(ws + OFF_AL);
    float* w_anorm = (float*)(ws + OFF_ANORM);
    float* w_bnorm = (float*)(ws + OFF_BNORM);
    float* w_nmf2  = (float*)(ws + OFF_NMF2);
    float* w_updf  = (float*)(ws + OFF_UPDF);
    int*   w_gtc   = (int*)(ws + OFF_GTC);
    int*   w_smi   = (int*)(ws + OFF_SMI);
    int*   w_perm  = (int*)(ws + OFF_PERM);
    float* w_midf  = (float*)(ws + OFF_MIDF);
    float* w_midn2 = (float*)(ws + OFF_MIDN2);
    float* w_midc  = (float*)(ws + OFF_MIDC);
    int*   w_cls   = (int*)(ws + OFF_CLS);
    float* w_pav   = (float*)(ws + OFF_PAV);
    int*   w_pai   = (int*)(ws + OFF_PAI);
    float* w_uwacc = (float*)(ws + OFF_UWACC);
    float* w_vals  = (float*)(ws + OFF_VALS);
    int*   w_pos   = (int*)(ws + OFF_POS);
    float* w_maxv  = (float*)(ws + OFF_MAXV);
    int*   w_amax  = (int*)(ws + OFF_AMAX);
    int*   w_flags = (int*)(ws + OFF_FLAGS);
    int*   w_cnt   = (int*)(ws + OFF_CNT);
    int*   w_meta  = (int*)(ws + OFF_META);

    hipMemsetAsync(w_pos, 0xFF, (size_t)N*4, stream);   // -1
    hipMemsetAsync(w_flags, 0, 8, stream);
    hipMemsetAsync(w_cnt, 0, OUT*4, stream);
    hipMemsetAsync(w_uwacc, 0, (size_t)N*OUT*4, stream);

    k_diff<<<1, 64, 0, stream>>>(posses, w_diff);
    k_prep_m<<<M/256, 256, 0, stream>>>(ssf, scoords, gt, ran, w_diff,
                                        w_al, w_anorm, w_updf, w_gtc);
    k_prep_n<<<N/256, 256, 0, stream>>>(mf, w_bnorm, w_nmf2);
    k_argmin<<<dim3(M/256, NSPA), 256, 0, stream>>>(w_anorm, w_bnorm, w_al, ori,
                                                    w_pav, w_pai);
    k_argmin_reduce<<<M/256, 256, 0, stream>>>(w_pav, w_pai, w_smi, out_smi);
    k_hist<<<M/256, 256, 0, stream>>>(w_gtc, w_updf, w_cnt);
    k_scan<<<1, 64, 0, stream>>>(w_cnt, w_meta);
    k_permute<<<M/256, 256, 0, stream>>>(w_gtc, w_updf, w_meta, w_perm);
    k_gather_sorted<<<M/256, 256, 0, stream>>>(w_meta, w_perm, w_smi, w_gtc,
                                               mf, w_nmf2, ori,
                                               w_midf, w_midn2, w_midc, w_cls);
    k_uw<<<dim3(N/256, NSPB), 256, 0, stream>>>(mf, w_nmf2, ori, w_midf, w_midn2,
                                                w_midc, w_cls, w_meta, w_uwacc);
    k_uw_final<<<N/256, 256, 0, stream>>>(w_uwacc, svp, out_uw, out_spu);
    k_scatter_pre<<<LG/256, 256, 0, stream>>>(w_smi, w_gtc, out_spu, w_vals, w_pos, w_flags);
    k_scatter_apply<<<LG/256, 256, 0, stream>>>(w_smi, w_gtc, w_vals, w_pos, w_flags, out_spu);
    k_trust_pre<<<N/256, 256, 0, stream>>>(out_spu, w_maxv, w_amax, w_flags);
    k_finalize<<<N/256, 256, 0, stream>>>(mf, ori, w_maxv, w_amax, w_flags,
                                          out_trust, out_mf, out_ori, out_pre);
}

// Round 6
// 384.656 us; speedup vs baseline: 2.0688x; 2.0688x over previous
//
#include <hip/hip_runtime.h>
#include <math.h>

#define N 8192
#define M 8192
#define C 96
#define OUT 20
#define LG 2048

#define KP 288      // packed K: [hi|hi|lo] x [hi|lo|hi], 3 sections of 96
#define SAP 104     // LDS row pitch (fp16 elems): 96 + 8 pad
#define NTA 64      // n-tiles in pass A (N/128)
#define NSPB 8      // m-tile stride (slices) in pass B

typedef _Float16 h8 __attribute__((ext_vector_type(8)));
typedef float    f4 __attribute__((ext_vector_type(4)));

// ---------------- workspace layout (bytes, all 256-aligned) ----------------
constexpr size_t OFF_DIFF  = 0;
constexpr size_t OFF_AL    = 256;
constexpr size_t OFF_NMF2  = OFF_AL    + (size_t)M*3*4;
constexpr size_t OFF_UPDF  = OFF_NMF2  + (size_t)N*4;
constexpr size_t OFF_GTC   = OFF_UPDF  + (size_t)M*4;
constexpr size_t OFF_SMI   = OFF_GTC   + (size_t)M*4;
constexpr size_t OFF_PERM  = OFF_SMI   + (size_t)M*4;
constexpr size_t OFF_AP    = OFF_PERM  + (size_t)M*4;            // M x 288 fp16
constexpr size_t OFF_BQ    = OFF_AP    + (size_t)M*KP*2;         // N x 288 fp16
constexpr size_t OFF_MFP   = OFF_BQ    + (size_t)N*KP*2;         // N x 288 fp16
constexpr size_t OFF_MIDQ  = OFF_MFP   + (size_t)N*KP*2;         // (M+128) x 288 fp16
constexpr size_t OFF_MIDN2 = OFF_MIDQ  + (size_t)(M+128)*KP*2;
constexpr size_t OFF_MIDC  = OFF_MIDN2 + (size_t)(M+128)*4;
constexpr size_t OFF_CLS   = OFF_MIDC  + (size_t)(M+128)*3*4;
constexpr size_t OFF_PAV   = OFF_CLS   + (size_t)(M+128)*4;      // NTA x M
constexpr size_t OFF_PAI   = OFF_PAV   + (size_t)NTA*M*4;
constexpr size_t OFF_PB    = OFF_PAI   + (size_t)NTA*M*4;        // NSPB x N x 20
constexpr size_t OFF_VALS  = OFF_PB    + (size_t)NSPB*N*OUT*4;
constexpr size_t OFF_POS   = OFF_VALS  + (size_t)LG*4;
constexpr size_t OFF_MAXV  = OFF_POS   + (size_t)N*4;
constexpr size_t OFF_AMAX  = OFF_MAXV  + (size_t)N*4;
constexpr size_t OFF_FLAGS = OFF_AMAX  + (size_t)N*4;
constexpr size_t OFF_CNT   = OFF_FLAGS + 256;
constexpr size_t OFF_META  = OFF_CNT   + 256;   // [0]=Mact [1]=ntiles [2..21]=cursor

// ---------------------------------------------------------------- 4x4 inverse
__global__ void k_diff(const float* __restrict__ posses, float* __restrict__ diff) {
    if (threadIdx.x != 0 || blockIdx.x != 0) return;
    float a[4][8];
    for (int i = 0; i < 4; i++)
        for (int j = 0; j < 4; j++) {
            a[i][j]     = posses[16 + i*4 + j];
            a[i][4 + j] = (i == j) ? 1.f : 0.f;
        }
    for (int col = 0; col < 4; col++) {
        int piv = col; float mx = fabsf(a[col][col]);
        for (int r = col + 1; r < 4; r++) {
            float v = fabsf(a[r][col]);
            if (v > mx) { mx = v; piv = r; }
        }
        if (piv != col)
            for (int j = 0; j < 8; j++) { float t = a[col][j]; a[col][j] = a[piv][j]; a[piv][j] = t; }
        float inv = 1.0f / a[col][col];
        for (int j = 0; j < 8; j++) a[col][j] *= inv;
        for (int r = 0; r < 4; r++) {
            if (r == col) continue;
            float f = a[r][col];
            for (int j = 0; j < 8; j++) a[r][j] -= f * a[col][j];
        }
    }
    for (int i = 0; i < 4; i++)
        for (int j = 0; j < 4; j++) {
            float s = 0.f;
            for (int k = 0; k < 4; k++) s += a[i][4 + k] * posses[k*4 + j];
            diff[i*4 + j] = s;
        }
}

// ---------------------------------------------------------------- per-m prep
__global__ void k_prep_m(const float* __restrict__ ssf, const float* __restrict__ scoords,
                         const float* __restrict__ gt, const int* __restrict__ ran_mask,
                         const float* __restrict__ diff,
                         float* __restrict__ al, _Float16* __restrict__ aP,
                         float* __restrict__ updf, int* __restrict__ gtcls) {
    int m = blockIdx.x * 256 + threadIdx.x;
    if (m >= M) return;
    float x = scoords[m*3], y = scoords[m*3+1], z = scoords[m*3+2];
    #pragma unroll
    for (int j = 0; j < 3; j++)
        al[m*3 + j] = diff[j*4+0]*x + diff[j*4+1]*y + diff[j*4+2]*z + diff[j*4+3];
    const float4* r4 = (const float4*)(ssf + (size_t)m * C);
    float4 row[24]; float s = 0.f;
    #pragma unroll
    for (int c = 0; c < 24; c++) {
        float4 v = r4[c];
        row[c] = v;
        s += v.x*v.x + v.y*v.y + v.z*v.z + v.w*v.w;
    }
    float scale = 256.0f / sqrtf(s);
    h8* dst = (h8*)(aP + (size_t)m * KP);
    #pragma unroll
    for (int q = 0; q < 12; q++) {
        float4 u = row[2*q], v = row[2*q+1];
        float xs[8] = {u.x,u.y,u.z,u.w,v.x,v.y,v.z,v.w};
        h8 hi, lo;
        #pragma unroll
        for (int e = 0; e < 8; e++) {
            float xv = xs[e] * scale;
            _Float16 h = (_Float16)xv;
            hi[e] = h;
            lo[e] = (_Float16)(xv - (float)h);
        }
        dst[q] = hi; dst[12+q] = hi; dst[24+q] = lo;
    }
    int best = 0; float bv = gt[(size_t)m*OUT];
    #pragma unroll
    for (int k = 1; k < OUT; k++) {
        float v = gt[(size_t)m*OUT + k];
        if (v > bv) { bv = v; best = k; }
    }
    gtcls[m] = best;
    updf[m] = (best < 9 || m < LG || ran_mask[m] == 1) ? 1.f : 0.f;
}

// ---------------------------------------------------------------- per-n prep
__global__ void k_prep_n(const float* __restrict__ mf, _Float16* __restrict__ bQ,
                         _Float16* __restrict__ mfP, float* __restrict__ nmf2) {
    int n = blockIdx.x * 256 + threadIdx.x;
    if (n >= N) return;
    const float4* r4 = (const float4*)(mf + (size_t)n * C);
    float4 row[24]; float s = 0.f;
    #pragma unroll
    for (int c = 0; c < 24; c++) {
        float4 v = r4[c];
        row[c] = v;
        s += v.x*v.x + v.y*v.y + v.z*v.z + v.w*v.w;
    }
    nmf2[n] = s;
    float scn = 256.0f / sqrtf(s);
    h8* dB = (h8*)(bQ  + (size_t)n * KP);
    h8* dF = (h8*)(mfP + (size_t)n * KP);
    #pragma unroll
    for (int q = 0; q < 12; q++) {
        float4 u = row[2*q], v = row[2*q+1];
        float xs[8] = {u.x,u.y,u.z,u.w,v.x,v.y,v.z,v.w};
        h8 hiN, loN, hiF, loF;
        #pragma unroll
        for (int e = 0; e < 8; e++) {
            float xn = xs[e] * scn;
            _Float16 hn = (_Float16)xn;
            hiN[e] = hn; loN[e] = (_Float16)(xn - (float)hn);
            float xf = xs[e] * 256.0f;
            _Float16 hf = (_Float16)xf;
            hiF[e] = hf; loF[e] = (_Float16)(xf - (float)hf);
        }
        dB[q] = hiN; dB[12+q] = loN; dB[24+q] = hiN;   // Q-pattern
        dF[q] = hiF; dF[12+q] = hiF; dF[24+q] = loF;   // P-pattern
    }
}

// ---------------------------------------------------------------- pass A: MFMA argmin
// 128m x 128n tile, 4 waves 2x2, each wave 4x4 of 16x16x32_f16 tiles, K=288 in 3 chunks.
// Cross-wn combine via LDS (wn=0 deposits, wn=1 merges+writes) -- single writer per (tile,m).
__global__ __launch_bounds__(256, 2) void k_argmin(
        const _Float16* __restrict__ aP, const _Float16* __restrict__ bQ,
        const float* __restrict__ al, const float* __restrict__ ori,
        float* __restrict__ pav, int* __restrict__ pai) {
    __shared__ _Float16 sA[128*SAP];
    __shared__ _Float16 sB[128*SAP];
    __shared__ float s_mc[128*3], s_nc[128*3];
    __shared__ float xv[128];
    __shared__ int   xi[128];
    const int t = threadIdx.x;
    const int wave = t >> 6, lane = t & 63;
    const int col = lane & 15, quad = lane >> 4;
    const int wm = wave >> 1, wn = wave & 1;
    const int m0 = blockIdx.x * 128, n0 = blockIdx.y * 128;

    for (int i = t; i < 384; i += 256) {
        s_mc[i] = al[(size_t)m0*3 + i];
        s_nc[i] = ori[(size_t)n0*3 + i];
    }

    f4 acc[4][4];
    #pragma unroll
    for (int i = 0; i < 4; i++)
        #pragma unroll
        for (int j = 0; j < 4; j++) acc[i][j] = (f4){0.f,0.f,0.f,0.f};

    const int r = t >> 1, h = t & 1;
    for (int kc = 0; kc < 3; kc++) {
        __syncthreads();
        {
            const h8* srcA = (const h8*)(aP + (size_t)(m0 + r)*KP + kc*96 + h*48);
            const h8* srcB = (const h8*)(bQ + (size_t)(n0 + r)*KP + kc*96 + h*48);
            h8* dA = (h8*)(sA + r*SAP + h*48);
            h8* dB = (h8*)(sB + r*SAP + h*48);
            #pragma unroll
            for (int q = 0; q < 6; q++) { dA[q] = srcA[q]; dB[q] = srcB[q]; }
        }
        __syncthreads();
        #pragma unroll
        for (int ks = 0; ks < 3; ks++) {
            h8 af[4], bf[4];
            #pragma unroll
            for (int i = 0; i < 4; i++)
                af[i] = *(const h8*)(sA + (wm*64 + i*16 + col)*SAP + ks*32 + quad*8);
            #pragma unroll
            for (int j = 0; j < 4; j++)
                bf[j] = *(const h8*)(sB + (wn*64 + j*16 + col)*SAP + ks*32 + quad*8);
            #pragma unroll
            for (int i = 0; i < 4; i++)
                #pragma unroll
                for (int j = 0; j < 4; j++)
                    acc[i][j] = __builtin_amdgcn_mfma_f32_16x16x32_f16(af[i], bf[j], acc[i][j], 0, 0, 0);
        }
    }

    // epilogue: sim + per-row argmin (rows m: ti,quad,g; cols n: tj,col)
    float best[4][4]; int bidx[4][4];
    #pragma unroll
    for (int i = 0; i < 4; i++)
        #pragma unroll
        for (int g = 0; g < 4; g++) { best[i][g] = 3.4e38f; bidx[i][g] = 0; }

    #pragma unroll
    for (int tj = 0; tj < 4; tj++) {
        int nl = wn*64 + tj*16 + col;
        int n  = n0 + nl;
        float ncx = s_nc[nl*3+0], ncy = s_nc[nl*3+1], ncz = s_nc[nl*3+2];
        #pragma unroll
        for (int ti = 0; ti < 4; ti++) {
            #pragma unroll
            for (int g = 0; g < 4; g++) {
                int ml = wm*64 + ti*16 + quad*4 + g;
                float dot = acc[ti][tj][g] * (1.0f/65536.0f);
                float dx = s_mc[ml*3+0]-ncx, dy = s_mc[ml*3+1]-ncy, dz = s_mc[ml*3+2]-ncz;
                float d2 = dx*dx + dy*dy + dz*dz;
                float sim = 2.0f - dot - __expf(-2.0f*d2);
                if (sim < best[ti][g]) { best[ti][g] = sim; bidx[ti][g] = n; }
            }
        }
    }
    // butterfly over the 16 col-lanes: all lanes end with the reduced (val,idx)
    #pragma unroll
    for (int ti = 0; ti < 4; ti++) {
        #pragma unroll
        for (int g = 0; g < 4; g++) {
            float bv = best[ti][g]; int bi = bidx[ti][g];
            #pragma unroll
            for (int d = 1; d < 16; d <<= 1) {
                float ov = __shfl_xor(bv, d, 64);
                int   oi = __shfl_xor(bi, d, 64);
                if (ov < bv || (ov == bv && oi < bi)) { bv = ov; bi = oi; }
            }
            best[ti][g] = bv; bidx[ti][g] = bi;
        }
    }
    __syncthreads();
    if (wn == 0 && col == 0) {
        #pragma unroll
        for (int ti = 0; ti < 4; ti++)
            #pragma unroll
            for (int g = 0; g < 4; g++) {
                int ml = wm*64 + ti*16 + quad*4 + g;
                xv[ml] = best[ti][g]; xi[ml] = bidx[ti][g];
            }
    }
    __syncthreads();
    if (wn == 1 && col == 0) {
        #pragma unroll
        for (int ti = 0; ti < 4; ti++)
            #pragma unroll
            for (int g = 0; g < 4; g++) {
                int ml = wm*64 + ti*16 + quad*4 + g;
                float bv = best[ti][g]; int bi = bidx[ti][g];
                float v0 = xv[ml]; int i0 = xi[ml];
                if (v0 < bv || (v0 == bv && i0 < bi)) { bv = v0; bi = i0; }
                pav[(size_t)blockIdx.y * M + m0 + ml] = bv;
                pai[(size_t)blockIdx.y * M + m0 + ml] = bi;
            }
    }
}

__global__ void k_argmin_reduce(const float* __restrict__ pav, const int* __restrict__ pai,
                                int* __restrict__ smi, float* __restrict__ out_smi) {
    int m = blockIdx.x * 256 + threadIdx.x;
    if (m >= M) return;
    float best = 3.4e38f; int bidx = 0;
    for (int sp = 0; sp < NTA; sp++) {
        float v = pav[(size_t)sp * M + m];
        int   i = pai[(size_t)sp * M + m];
        if (v < best || (v == best && i < bidx)) { best = v; bidx = i; }
    }
    smi[m] = bidx;
    out_smi[m] = (float)bidx;
}

// ---------------------------------------------------------------- counting sort by class
__global__ void k_hist(const int* __restrict__ gtcls, const float* __restrict__ updf,
                       int* __restrict__ cnt) {
    __shared__ int hcnt[OUT];
    int t = threadIdx.x;
    if (t < OUT) hcnt[t] = 0;
    __syncthreads();
    int m = blockIdx.x * 256 + t;
    if (m < M && updf[m] != 0.f) atomicAdd(&hcnt[gtcls[m]], 1);
    __syncthreads();
    if (t < OUT) atomicAdd(&cnt[t], hcnt[t]);
}

__global__ void k_scan(const int* __restrict__ cnt, int* __restrict__ meta) {
    if (threadIdx.x != 0 || blockIdx.x != 0) return;
    int run = 0;
    for (int k = 0; k < OUT; k++) { meta[2 + k] = run; run += cnt[k]; }
    meta[0] = run;
    meta[1] = (run + 127) / 128;
}

__global__ void k_permute(const int* __restrict__ gtcls, const float* __restrict__ updf,
                          int* __restrict__ meta, int* __restrict__ perm) {
    int m = blockIdx.x * 256 + threadIdx.x;
    if (m >= M) return;
    if (updf[m] == 0.f) return;
    int pos = atomicAdd(&meta[2 + gtcls[m]], 1);
    perm[pos] = m;
}

// gather sorted+compacted mid rows, Q-pattern reorder from mfP ([hi|hi|lo] -> [hi|lo|hi])
__global__ void k_gather_sorted(const int* __restrict__ meta, const int* __restrict__ perm,
                                const int* __restrict__ smi, const int* __restrict__ gtcls,
                                const _Float16* __restrict__ mfP, const float* __restrict__ nmf2,
                                const float* __restrict__ ori,
                                _Float16* __restrict__ midQ, float* __restrict__ midn2,
                                float* __restrict__ midc, int* __restrict__ cls_s) {
    int rr = blockIdx.x * 256 + threadIdx.x;
    int mact = meta[0];
    int mpad = meta[1] * 128;
    if (rr < mact) {
        int m = perm[rr];
        int s = smi[m];
        const h8* src = (const h8*)(mfP + (size_t)s * KP);
        h8* dst = (h8*)(midQ + (size_t)rr * KP);
        #pragma unroll
        for (int q = 0; q < 12; q++) {
            h8 hi = src[q], lo = src[24+q];
            dst[q] = hi; dst[12+q] = lo; dst[24+q] = hi;
        }
        midn2[rr] = nmf2[s];
        midc[rr*3+0] = ori[s*3+0];
        midc[rr*3+1] = ori[s*3+1];
        midc[rr*3+2] = ori[s*3+2];
        cls_s[rr] = gtcls[m];
    } else if (rr < mpad) {
        h8 z = (h8)(_Float16)0.f;
        h8* dst = (h8*)(midQ + (size_t)rr * KP);
        #pragma unroll
        for (int q = 0; q < 36; q++) dst[q] = z;
        midn2[rr] = 1e9f;     // w = exp(-5.55e9) == 0 exactly
        midc[rr*3+0] = 0.f; midc[rr*3+1] = 0.f; midc[rr*3+2] = 0.f;
        cls_s[rr] = 0;
    }
}

// ---------------------------------------------------------------- pass B: MFMA class-binned sums
__global__ __launch_bounds__(256, 2) void k_uw(
        const _Float16* __restrict__ mfP, const _Float16* __restrict__ midQ,
        const float* __restrict__ nmf2, const float* __restrict__ ori,
        const float* __restrict__ midn2, const float* __restrict__ midc,
        const int* __restrict__ cls_s, const int* __restrict__ meta,
        float* __restrict__ pb) {
    __shared__ _Float16 sM[128*SAP];   // mid rows  (MFMA A: rows m')
    __shared__ _Float16 sN[128*SAP];   // mf n-rows (MFMA B: rows n)
    __shared__ float bins[128*21];
    __shared__ float s_nc[128*3], s_mc[128*3];
    __shared__ float s_n2[128], s_m2[128];
    __shared__ int   s_cl[128];
    const int t = threadIdx.x;
    const int wave = t >> 6, lane = t & 63;
    const int col = lane & 15, quad = lane >> 4;
    const int wm = wave >> 1, wn = wave & 1;
    const int n0 = blockIdx.x * 128;
    const int sp = blockIdx.y;
    const int ntiles = meta[1];

    for (int i = t; i < 128*21; i += 256) bins[i] = 0.f;
    for (int i = t; i < 384; i += 256) s_nc[i] = ori[(size_t)n0*3 + i];
    if (t < 128) s_n2[t] = nmf2[n0 + t];

    const int r = t >> 1, h = t & 1;
    for (int mt = sp; mt < ntiles; mt += NSPB) {
        const int mb = mt * 128;
        __syncthreads();   // prev epilogue done before restaging aux
        if (t < 128) { s_m2[t] = midn2[mb + t]; s_cl[t] = cls_s[mb + t]; }
        for (int i = t; i < 384; i += 256) s_mc[i] = midc[(size_t)mb*3 + i];

        f4 acc[4][4];
        #pragma unroll
        for (int i = 0; i < 4; i++)
            #pragma unroll
            for (int j = 0; j < 4; j++) acc[i][j] = (f4){0.f,0.f,0.f,0.f};

        for (int kc = 0; kc < 3; kc++) {
            __syncthreads();
            {
                const h8* srcM = (const h8*)(midQ + (size_t)(mb + r)*KP + kc*96 + h*48);
                const h8* srcN = (const h8*)(mfP  + (size_t)(n0 + r)*KP + kc*96 + h*48);
                h8* dM = (h8*)(sM + r*SAP + h*48);
                h8* dN = (h8*)(sN + r*SAP + h*48);
                #pragma unroll
                for (int q = 0; q < 6; q++) { dM[q] = srcM[q]; dN[q] = srcN[q]; }
            }
            __syncthreads();
            #pragma unroll
            for (int ks = 0; ks < 3; ks++) {
                h8 af[4], bf[4];
                #pragma unroll
                for (int i = 0; i < 4; i++)
                    af[i] = *(const h8*)(sM + (wm*64 + i*16 + col)*SAP + ks*32 + quad*8);
                #pragma unroll
                for (int j = 0; j < 4; j++)
                    bf[j] = *(const h8*)(sN + (wn*64 + j*16 + col)*SAP + ks*32 + quad*8);
                #pragma unroll
                for (int i = 0; i < 4; i++)
                    #pragma unroll
                    for (int j = 0; j < 4; j++)
                        acc[i][j] = __builtin_amdgcn_mfma_f32_16x16x32_f16(af[i], bf[j], acc[i][j], 0, 0, 0);
            }
        }
        // epilogue: rows m' (ti,quad,g) ascending per lane -> run-length flush by class
        #pragma unroll
        for (int tj = 0; tj < 4; tj++) {
            int nl = wn*64 + tj*16 + col;
            float n2 = s_n2[nl];
            float ncx = s_nc[nl*3+0], ncy = s_nc[nl*3+1], ncz = s_nc[nl*3+2];
            float cur = 0.f; int curc = -1;
            #pragma unroll
            for (int ti = 0; ti < 4; ti++) {
                #pragma unroll
                for (int g = 0; g < 4; g++) {
                    int ml = wm*64 + ti*16 + quad*4 + g;
                    float dot = acc[ti][tj][g] * (1.0f/65536.0f);
                    float fd = fmaxf(n2 + s_m2[ml] - 2.0f*dot, 0.0f);
                    float dx = ncx - s_mc[ml*3+0], dy = ncy - s_mc[ml*3+1], dz = ncz - s_mc[ml*3+2];
                    float dc = dx*dx + dy*dy + dz*dz;
                    float w = __expf(-8.0f*dc - (0.5f/0.09f)*fd);
                    int c = s_cl[ml];
                    if (c != curc) {
                        if (curc >= 0) atomicAdd(&bins[nl*21 + curc], cur);
                        curc = c; cur = 0.f;
                    }
                    cur += w;
                }
            }
            if (curc >= 0) atomicAdd(&bins[nl*21 + curc], cur);
        }
    }
    __syncthreads();
    for (int i = t; i < 128*OUT; i += 256) {
        int loc = i / OUT, k = i - loc*OUT;
        pb[((size_t)sp*N + n0 + loc)*OUT + k] = bins[loc*21 + k];
    }
}

__global__ void k_uw_final(const float* __restrict__ pb, const float* __restrict__ svp,
                           float* __restrict__ out_uw, float* __restrict__ out_spu) {
    int n = blockIdx.x * 256 + threadIdx.x;
    if (n >= N) return;
    float s[OUT];
    #pragma unroll
    for (int k = 0; k < OUT; k++) s[k] = 0.f;
    for (int sp = 0; sp < NSPB; sp++) {
        size_t base = ((size_t)sp * N + n) * OUT;
        #pragma unroll
        for (int k = 0; k < OUT; k++) s[k] += pb[base + k];
    }
    float tot = 0.f;
    #pragma unroll
    for (int k = 0; k < OUT; k++) tot += s[k];
    float rden = 1.0f / (tot + 1e-16f);
    float p[OUT]; float mx = -3.4e38f;
    #pragma unroll
    for (int k = 0; k < OUT; k++) { p[k] = svp[(size_t)n*OUT + k]; mx = fmaxf(mx, p[k]); }
    float es = 0.f;
    #pragma unroll
    for (int k = 0; k < OUT; k++) { p[k] = __expf(p[k] - mx); es += p[k]; }
    float res = 1.0f / es;
    #pragma unroll
    for (int k = 0; k < OUT; k++) {
        float uw = s[k] * rden;
        out_uw[(size_t)n*OUT + k] = uw;
        out_spu[(size_t)n*OUT + k] = 0.5f * (p[k] * res) + 0.5f * uw;
    }
}

// ---------------------------------------------------------------- scatter (lg rows, last-wins)
__global__ void k_scatter_pre(const int* __restrict__ smi, const int* __restrict__ gtcls,
                              const float* __restrict__ spu, float* __restrict__ vals,
                              int* __restrict__ pos, int* __restrict__ flags) {
    int i = blockIdx.x * 256 + threadIdx.x;
    if (i >= LG) return;
    int idx = smi[i];
    float v = spu[(size_t)idx*OUT + gtcls[i]];
    vals[i] = v;
    if (v > 0.1f) atomicOr(&flags[0], 1);
    atomicMax(&pos[idx], i);
}

__global__ void k_scatter_apply(const int* __restrict__ smi, const int* __restrict__ gtcls,
                                const float* __restrict__ vals, const int* __restrict__ pos,
                                const int* __restrict__ flags, float* __restrict__ spu) {
    int i = blockIdx.x * 256 + threadIdx.x;
    if (i >= LG) return;
    int idx = smi[i];
    if (pos[idx] != i) return;
    float v = vals[i];
    bool tmp = flags[0] ? (v > 0.1f) : (v > 0.0f);
    if (!tmp) return;
    int cls = gtcls[i];
    #pragma unroll
    for (int k = 0; k < OUT; k++) spu[(size_t)idx*OUT + k] = (k == cls) ? 1.0f : 0.0f;
}

// ---------------------------------------------------------------- trust / finalize
__global__ void k_trust_pre(const float* __restrict__ spu, float* __restrict__ maxv,
                            int* __restrict__ amax, int* __restrict__ flags) {
    int n = blockIdx.x * 256 + threadIdx.x;
    if (n >= N) return;
    float best = spu[(size_t)n*OUT]; int bi = 0;
    #pragma unroll
    for (int k = 1; k < OUT; k++) {
        float v = spu[(size_t)n*OUT + k];
        if (v > best) { best = v; bi = k; }
    }
    maxv[n] = best; amax[n] = bi;
    if (best >= 0.9f) atomicOr(&flags[1], 1);
}

__global__ void k_finalize(const float* __restrict__ mf, const float* __restrict__ ori,
                           const float* __restrict__ maxv, const int* __restrict__ amax,
                           const int* __restrict__ flags,
                           float* __restrict__ out_trust, float* __restrict__ out_mf,
                           float* __restrict__ out_ori, float* __restrict__ out_pre) {
    int n = blockIdx.x * 256 + threadIdx.x;
    if (n >= N) return;
    float mv = maxv[n];
    bool tr = flags[1] ? (mv >= 0.9f) : (mv >= 0.85f);
    float m = tr ? 1.f : 0.f;
    out_trust[n] = m;
    const float4* src = (const float4*)(mf + (size_t)n * C);
    float4* dst = (float4*)(out_mf + (size_t)n * C);
    #pragma unroll
    for (int c = 0; c < 24; c++) {
        float4 v = src[c];
        v.x *= m; v.y *= m; v.z *= m; v.w *= m;
        dst[c] = v;
    }
    out_ori[n*3]   = ori[n*3]   * m;
    out_ori[n*3+1] = ori[n*3+1] * m;
    out_ori[n*3+2] = ori[n*3+2] * m;
    int bi = amax[n];
    #pragma unroll
    for (int k = 0; k < OUT; k++) out_pre[(size_t)n*OUT + k] = (k == bi) ? m : 0.f;
}

// ---------------------------------------------------------------- launch
extern "C" void kernel_launch(void* const* d_in, const int* in_sizes, int n_in,
                              void* d_out, int out_size, void* d_ws, size_t ws_size,
                              hipStream_t stream) {
    (void)in_sizes; (void)n_in; (void)out_size; (void)ws_size;
    const float* ssf     = (const float*)d_in[0];
    const float* scoords = (const float*)d_in[1];
    const float* gt      = (const float*)d_in[2];
    const float* svp     = (const float*)d_in[3];
    const float* mf      = (const float*)d_in[4];
    const float* ori     = (const float*)d_in[5];
    const float* posses  = (const float*)d_in[6];
    const int*   ran     = (const int*)d_in[7];

    float* out = (float*)d_out;
    float* out_trust = out;
    float* out_mf    = out_trust + N;
    float* out_ori   = out_mf + (size_t)N*C;
    float* out_pre   = out_ori + (size_t)N*3;
    float* out_uw    = out_pre + (size_t)N*OUT;
    float* out_spu   = out_uw  + (size_t)N*OUT;
    float* out_smi   = out_spu + (size_t)N*OUT;

    char* ws = (char*)d_ws;
    float*     w_diff  = (float*)(ws + OFF_DIFF);
    float*     w_al    = (float*)(ws + OFF_AL);
    float*     w_nmf2  = (float*)(ws + OFF_NMF2);
    float*     w_updf  = (float*)(ws + OFF_UPDF);
    int*       w_gtc   = (int*)(ws + OFF_GTC);
    int*       w_smi   = (int*)(ws + OFF_SMI);
    int*       w_perm  = (int*)(ws + OFF_PERM);
    _Float16*  w_aP    = (_Float16*)(ws + OFF_AP);
    _Float16*  w_bQ    = (_Float16*)(ws + OFF_BQ);
    _Float16*  w_mfP   = (_Float16*)(ws + OFF_MFP);
    _Float16*  w_midQ  = (_Float16*)(ws + OFF_MIDQ);
    float*     w_midn2 = (float*)(ws + OFF_MIDN2);
    float*     w_midc  = (float*)(ws + OFF_MIDC);
    int*       w_cls   = (int*)(ws + OFF_CLS);
    float*     w_pav   = (float*)(ws + OFF_PAV);
    int*       w_pai   = (int*)(ws + OFF_PAI);
    float*     w_pb    = (float*)(ws + OFF_PB);
    float*     w_vals  = (float*)(ws + OFF_VALS);
    int*       w_pos   = (int*)(ws + OFF_POS);
    float*     w_maxv  = (float*)(ws + OFF_MAXV);
    int*       w_amax  = (int*)(ws + OFF_AMAX);
    int*       w_flags = (int*)(ws + OFF_FLAGS);
    int*       w_cnt   = (int*)(ws + OFF_CNT);
    int*       w_meta  = (int*)(ws + OFF_META);

    hipMemsetAsync(w_pos, 0xFF, (size_t)N*4, stream);   // -1
    hipMemsetAsync(w_flags, 0, 8, stream);
    hipMemsetAsync(w_cnt, 0, OUT*4, stream);

    k_diff<<<1, 64, 0, stream>>>(posses, w_diff);
    k_prep_m<<<M/256, 256, 0, stream>>>(ssf, scoords, gt, ran, w_diff,
                                        w_al, w_aP, w_updf, w_gtc);
    k_prep_n<<<N/256, 256, 0, stream>>>(mf, w_bQ, w_mfP, w_nmf2);
    k_argmin<<<dim3(M/128, NTA), 256, 0, stream>>>(w_aP, w_bQ, w_al, ori, w_pav, w_pai);
    k_argmin_reduce<<<M/256, 256, 0, stream>>>(w_pav, w_pai, w_smi, out_smi);
    k_hist<<<M/256, 256, 0, stream>>>(w_gtc, w_updf, w_cnt);
    k_scan<<<1, 64, 0, stream>>>(w_cnt, w_meta);
    k_permute<<<M/256, 256, 0, stream>>>(w_gtc, w_updf, w_meta, w_perm);
    k_gather_sorted<<<(M+128)/256, 256, 0, stream>>>(w_meta, w_perm, w_smi, w_gtc,
                                                     w_mfP, w_nmf2, ori,
                                                     w_midQ, w_midn2, w_midc, w_cls);
    k_uw<<<dim3(N/128, NSPB), 256, 0, stream>>>(w_mfP, w_midQ, w_nmf2, ori,
                                                w_midn2, w_midc, w_cls, w_meta, w_pb);
    k_uw_final<<<N/256, 256, 0, stream>>>(w_pb, svp, out_uw, out_spu);
    k_scatter_pre<<<LG/256, 256, 0, stream>>>(w_smi, w_gtc, out_spu, w_vals, w_pos, w_flags);
    k_scatter_apply<<<LG/256, 256, 0, stream>>>(w_smi, w_gtc, w_vals, w_pos, w_flags, out_spu);
    k_trust_pre<<<N/256, 256, 0, stream>>>(out_spu, w_maxv, w_amax, w_flags);
    k_finalize<<<N/256, 256, 0, stream>>>(mf, ori, w_maxv, w_amax, w_flags,
                                          out_trust, out_mf, out_ori, out_pre);
}